// Round 15
// baseline (1661.544 us; speedup 1.0000x reference)
//
#include <hip/hip_runtime.h>

// out[n,k] = softmax_k( 2*x_n.c_k - ||c_k||^2 )   (x_sqr cancels in softmax)
// 3-product bf16 split GEMM (logical K = 3*512 = 1536), 256x256 tiles,
// 4 phases/K-tile, k-slice stage units, counted vmcnt(4) closes (r7 GEMM,
// verbatim: best measured 1045us, 0 bank conflicts).
// Round 15: pipeline trim -- ONE fused prep kernel (split x + split cb +
// cb row-sq), combine folded into the norm kernel (8 rows/block, partials
// reduced in-register, per-(row,bn) scale computed locally). 3 launches.

typedef __attribute__((ext_vector_type(8))) __bf16 bf16x8;
typedef __attribute__((ext_vector_type(4))) float f32x4;

typedef __attribute__((address_space(1))) const void global_cvoid;
typedef __attribute__((address_space(3))) void lds_void;

__device__ inline unsigned short f32_to_bf16_rne(float f) {
    unsigned int u = __float_as_uint(f);
    unsigned int r = u + 0x7FFFu + ((u >> 16) & 1u);
    return (unsigned short)(r >> 16);
}
__device__ inline float bf16u_to_f32(unsigned short h) {
    return __uint_as_float(((unsigned int)h) << 16);
}

// ---------------- fused prep: split X and C to bf16 hi/lo, cb row-sq ----------------
// grid 10240 x 256: rows 0..32767 = x, 32768..40959 = codebook.
__global__ void prep_kernel(const float* __restrict__ x, const float* __restrict__ cb,
                            unsigned short* __restrict__ Xh, unsigned short* __restrict__ Xl,
                            unsigned short* __restrict__ Ch, unsigned short* __restrict__ Cl,
                            float* __restrict__ cbq) {
    int row = blockIdx.x * 4 + (threadIdx.x >> 6);
    int lane = threadIdx.x & 63;
    const bool isCb = (row >= 32768);
    const int r = isCb ? (row - 32768) : row;
    const float* src = (isCb ? cb : x) + (size_t)r * 512;
    unsigned short* hi = (isCb ? Ch : Xh) + (size_t)r * 512;
    unsigned short* lo = (isCb ? Cl : Xl) + (size_t)r * 512;

    float4 a = reinterpret_cast<const float4*>(src)[lane];
    float4 b = reinterpret_cast<const float4*>(src)[lane + 64];
    float va[8] = {a.x, a.y, a.z, a.w, b.x, b.y, b.z, b.w};
    unsigned short h[8], l[8];
    float sq = 0.f;
#pragma unroll
    for (int j = 0; j < 8; ++j) {
        h[j] = f32_to_bf16_rne(va[j]);
        l[j] = f32_to_bf16_rne(va[j] - bf16u_to_f32(h[j]));
        sq += va[j] * va[j];
    }
    ushort4 h0 = {h[0], h[1], h[2], h[3]}, h1 = {h[4], h[5], h[6], h[7]};
    ushort4 l0 = {l[0], l[1], l[2], l[3]}, l1 = {l[4], l[5], l[6], l[7]};
    *reinterpret_cast<ushort4*>(hi + lane * 4) = h0;
    *reinterpret_cast<ushort4*>(hi + (lane + 64) * 4) = h1;
    *reinterpret_cast<ushort4*>(lo + lane * 4) = l0;
    *reinterpret_cast<ushort4*>(lo + (lane + 64) * 4) = l1;
    if (isCb) {
#pragma unroll
        for (int o = 32; o >= 1; o >>= 1) sq += __shfl_xor(sq, o);
        if (lane == 0) cbq[r] = sq;
    }
}

// ---------------- GEMM 256x256 (r7, verbatim) ----------------
// Grid 4096 (128 bm x 32 bn, bijective XCD swizzle), 512 threads = 8 waves (2x4).
// LDS: lds[buf][mat A/B][kk][256 rows x 32 k bf16] = 128 KiB. 24 K-tiles of BK=64.
// Swizzle: 16B-slot col c_phys = c_log ^ ((row>>1)&3) (0-conflict, r7-verified).

#define RD_A(mq_, kk_, b_)                                                        \
    { _Pragma("unroll") for (int m = 0; m < 4; ++m)                               \
        afr[m] = *(const bf16x8*)&lds[b_][0][kk_][(a_slot + ((mq_)*4 + m) * 64) * 8]; }

#define RD_B(kk_, b_)                                                             \
    { _Pragma("unroll") for (int n = 0; n < 4; ++n)                               \
        bfr[n] = *(const bf16x8*)&lds[b_][1][kk_][(b_slot + n * 64) * 8]; }

#define ST(mat_, kk_, b_, tt_)                                                    \
    { int prod_ = (tt_) >> 3, ch_ = (tt_) & 7;                                    \
      const unsigned short* bse_;                                                 \
      if ((mat_) == 0) bse_ = (prod_ < 2 ? Ah : Al) + arow0;                      \
      else             bse_ = (prod_ == 1 ? Bl : Bh) + brow0;                     \
      bse_ += ch_ * 64 + (kk_) * 32;                                              \
      _Pragma("unroll") for (int j = 0; j < 2; ++j)                               \
          __builtin_amdgcn_global_load_lds((global_cvoid*)(bse_ + goff[j]),       \
              (lds_void*)&lds[b_][mat_][kk_][sl8[j]], 16, 0, 0);                  \
    }

#define MM(mq_)                                                                   \
    { _Pragma("unroll") for (int m = 0; m < 4; ++m)                               \
      _Pragma("unroll") for (int n = 0; n < 4; ++n)                               \
          acc[(mq_) * 4 + m][n] = __builtin_amdgcn_mfma_f32_16x16x32_bf16(        \
              afr[m], bfr[n], acc[(mq_) * 4 + m][n], 0, 0, 0); }

#define MIDSYNC()                                                                 \
    { __builtin_amdgcn_s_barrier();                                               \
      asm volatile("s_waitcnt lgkmcnt(0)" ::: "memory"); }

__global__ __launch_bounds__(512, 2) void gemm_kernel(
    const unsigned short* __restrict__ Ah, const unsigned short* __restrict__ Al,
    const unsigned short* __restrict__ Bh, const unsigned short* __restrict__ Bl,
    const float* __restrict__ cbq, unsigned short* __restrict__ p16,
    float* __restrict__ max_part, float* __restrict__ sum_part) {
    __shared__ __align__(16) unsigned short lds[2][2][2][8192];  // 128 KiB

    const int t = threadIdx.x;
    const int lane = t & 63;
    const int w = t >> 6;
    const int wm = w >> 2, wn = w & 3;  // 2 x 4 waves, each owns 128x64 output
    const int fr = lane & 15, fg = lane >> 4;

    int bid = blockIdx.x;
    int swz = (bid & 7) * 512 + (bid >> 3);  // 4096 % 8 == 0 -> bijective
    const int bm = swz >> 5, bn = swz & 31;
    const int row0 = bm * 256, col0 = bn * 256;
    const size_t arow0 = (size_t)row0 * 512;
    const size_t brow0 = (size_t)col0 * 512;

    const int xsl = fg ^ ((fr >> 1) & 3);
    const int a_slot = (wm * 128 + fr) * 4 + xsl;  // + (mq*4+m)*64
    const int b_slot = (wn * 64 + fr) * 4 + xsl;   // + n*64

    int goff[2], sl8[2];
#pragma unroll
    for (int j = 0; j < 2; ++j) {
        int s = j * 512 + t;
        int r_ = s >> 2, cp_ = s & 3;
        int cl_ = cp_ ^ ((r_ >> 1) & 3);   // inverse of read-side XOR
        goff[j] = r_ * 512 + cl_ * 8;
        sl8[j] = s * 8;
    }

    f32x4 acc[8][4] = {};
    bf16x8 afr[4], bfr[4];

    // prologue: stage tile 0 (A-kk0, B-kk0, A-kk1, B-kk1) into buf 0
    ST(0, 0, 0, 0);
    ST(1, 0, 0, 0);
    ST(0, 1, 0, 0);
    ST(1, 1, 0, 0);
    asm volatile("s_waitcnt vmcnt(4)\n\ts_barrier" ::: "memory");  // kk0 units landed

    for (int tt = 0; tt < 24; ++tt) {
        const int cur = tt & 1, nb = cur ^ 1;
        const bool pf = (tt < 23);
        // ---- phase 0: kk0, m0-3 ----
        RD_B(0, cur);
        RD_A(0, 0, cur);
        if (pf) ST(0, 0, nb, tt + 1);
        MIDSYNC();
        __builtin_amdgcn_s_setprio(1); MM(0); __builtin_amdgcn_s_setprio(0);
        __builtin_amdgcn_s_barrier();
        // ---- phase 1: kk0, m4-7 (B regs reused) ----
        RD_A(1, 0, cur);
        if (pf) ST(1, 0, nb, tt + 1);
        MIDSYNC();
        __builtin_amdgcn_s_setprio(1); MM(1); __builtin_amdgcn_s_setprio(0);
        if (pf) {
            asm volatile("s_waitcnt vmcnt(4)\n\ts_barrier" ::: "memory");
        } else {
            asm volatile("s_waitcnt vmcnt(0)\n\ts_barrier" ::: "memory");
        }
        // ---- phase 2: kk1, m0-3 ----
        RD_B(1, cur);
        RD_A(0, 1, cur);
        if (pf) ST(0, 1, nb, tt + 1);
        MIDSYNC();
        __builtin_amdgcn_s_setprio(1); MM(0); __builtin_amdgcn_s_setprio(0);
        __builtin_amdgcn_s_barrier();
        // ---- phase 3: kk1, m4-7 ----
        RD_A(1, 1, cur);
        if (pf) ST(1, 1, nb, tt + 1);
        MIDSYNC();
        __builtin_amdgcn_s_setprio(1); MM(1); __builtin_amdgcn_s_setprio(0);
        if (pf) {
            asm volatile("s_waitcnt vmcnt(4)\n\ts_barrier" ::: "memory");
        } else {
            __builtin_amdgcn_s_barrier();
        }
    }

    // ---- epilogue ----
    float* redm = (float*)&lds[0][0][0][0];
    float* reds = redm + 1024;

    float cq[4];
#pragma unroll
    for (int n = 0; n < 4; ++n) cq[n] = cbq[col0 + wn * 64 + n * 16 + fr];
#pragma unroll
    for (int m = 0; m < 8; ++m)
#pragma unroll
        for (int n = 0; n < 4; ++n)
#pragma unroll
            for (int r = 0; r < 4; ++r)
                acc[m][n][r] = 2.0f * acc[m][n][r] - cq[n];

    float rmx[8][4];
#pragma unroll
    for (int m = 0; m < 8; ++m)
#pragma unroll
        for (int r = 0; r < 4; ++r) {
            float v = fmaxf(fmaxf(acc[m][0][r], acc[m][1][r]),
                            fmaxf(acc[m][2][r], acc[m][3][r]));
#pragma unroll
            for (int o = 1; o < 16; o <<= 1) v = fmaxf(v, __shfl_xor(v, o));
            rmx[m][r] = v;
        }
    __syncthreads();
    if (fr == 0) {
#pragma unroll
        for (int m = 0; m < 8; ++m)
#pragma unroll
            for (int r = 0; r < 4; ++r)
                redm[wn * 256 + wm * 128 + m * 16 + fg * 4 + r] = rmx[m][r];
    }
    __syncthreads();
#pragma unroll
    for (int m = 0; m < 8; ++m)
#pragma unroll
        for (int r = 0; r < 4; ++r) {
            int row = wm * 128 + m * 16 + fg * 4 + r;
            rmx[m][r] = fmaxf(fmaxf(redm[row], redm[256 + row]),
                              fmaxf(redm[512 + row], redm[768 + row]));
        }
#pragma unroll
    for (int m = 0; m < 8; ++m)
#pragma unroll
        for (int r = 0; r < 4; ++r) {
            float s = 0.f;
#pragma unroll
            for (int n = 0; n < 4; ++n) s += __expf(acc[m][n][r] - rmx[m][r]);
#pragma unroll
            for (int o = 1; o < 16; o <<= 1) s += __shfl_xor(s, o);
            if (fr == 0) reds[wn * 256 + wm * 128 + m * 16 + fg * 4 + r] = s;
        }
    __syncthreads();
    if (wn == 0 && fr == 0) {
#pragma unroll
        for (int m = 0; m < 8; ++m)
#pragma unroll
            for (int r = 0; r < 4; ++r) {
                int row = wm * 128 + m * 16 + fg * 4 + r;
                size_t gr = (size_t)(row0 + row);
                max_part[gr * 32 + bn] = rmx[m][r];
                sum_part[gr * 32 + bn] =
                    reds[row] + reds[256 + row] + reds[512 + row] + reds[768 + row];
            }
    }
#pragma unroll
    for (int m = 0; m < 8; ++m)
#pragma unroll
        for (int n = 0; n < 4; ++n)
#pragma unroll
            for (int r = 0; r < 4; ++r) {
                size_t gr = (size_t)(row0 + wm * 128 + m * 16 + fg * 4 + r);
                size_t gi = gr * 8192 + col0 + wn * 64 + n * 16 + fr;
                union { _Float16 h; unsigned short u; } cv;
                cv.h = (_Float16)__expf(acc[m][n][r] - rmx[m][r]);
                p16[gi] = cv.u;
            }
}

// ---------------- fused combine+normalize: 8 rows per block ----------------
__global__ void norm_f16_kernel(const unsigned short* __restrict__ p16,
                                const float* __restrict__ max_part,
                                const float* __restrict__ sum_part,
                                float* __restrict__ out) {
    __shared__ float sscale[256];
    const int b = blockIdx.x;       // 4096 blocks x 8 rows
    const int i = threadIdx.x;      // 256
    const int rl = i >> 5, part = i & 31;
    const size_t row = (size_t)b * 8 + rl;

    // per-row global max + inv-sum from 32 partials (one per thread)
    float m = max_part[row * 32 + part];
    float s = sum_part[row * 32 + part];
    float gm = m;
#pragma unroll
    for (int o = 16; o >= 1; o >>= 1) gm = fmaxf(gm, __shfl_xor(gm, o, 32));
    float c = s * __expf(m - gm);
#pragma unroll
    for (int o = 16; o >= 1; o >>= 1) c += __shfl_xor(c, o, 32);
    sscale[i] = __expf(m - gm) / c;   // scale for (row rl, col-block part)
    __syncthreads();

    // normalize: 8 rows x 1024 groups of 8 = 8192 groups, 32 per thread
    const uint4* src = reinterpret_cast<const uint4*>(p16);
    float4* dst = reinterpret_cast<float4*>(out);
    const size_t gbase = (size_t)b * 8192;
#pragma unroll 4
    for (int k = 0; k < 32; ++k) {
        int idx = k * 256 + i;               // 0..8191
        int rloc = idx >> 10;                // local row
        int bn = (idx >> 5) & 31;            // col-block
        float sc = sscale[(rloc << 5) | bn];
        size_t g = gbase + idx;
        union { uint4 u; _Float16 h[8]; } cv;
        cv.u = src[g];
        float4 o1, o2;
        o1.x = (float)cv.h[0] * sc; o1.y = (float)cv.h[1] * sc;
        o1.z = (float)cv.h[2] * sc; o1.w = (float)cv.h[3] * sc;
        o2.x = (float)cv.h[4] * sc; o2.y = (float)cv.h[5] * sc;
        o2.z = (float)cv.h[6] * sc; o2.w = (float)cv.h[7] * sc;
        dst[g * 2] = o1;
        dst[g * 2 + 1] = o2;
    }
}

extern "C" void kernel_launch(void* const* d_in, const int* in_sizes, int n_in,
                              void* d_out, int out_size, void* d_ws, size_t ws_size,
                              hipStream_t stream) {
    const float* x = (const float*)d_in[0];   // [32768,512]
    const float* cb = (const float*)d_in[1];  // [8192,512]
    float* out = (float*)d_out;               // [32768,8192]
    char* ws = (char*)d_ws;

    unsigned short* Xh = (unsigned short*)(ws);                 // 33,554,432
    unsigned short* Xl = (unsigned short*)(ws + 33554432ull);   // 33,554,432
    unsigned short* Ch = (unsigned short*)(ws + 67108864ull);   // 8,388,608
    unsigned short* Cl = (unsigned short*)(ws + 75497472ull);   // 8,388,608
    float* cbq       = (float*)(ws + 83886080ull);              // 32,768
    float* max_part  = (float*)(ws + 83918848ull);              // 4,194,304
    float* sum_part  = (float*)(ws + 88113152ull);              // 4,194,304
    unsigned short* p16 = (unsigned short*)(ws + 96763904ull);  // 536,870,912 -> 633,634,816

    prep_kernel<<<10240, 256, 0, stream>>>(x, cb, Xh, Xl, Ch, Cl, cbq);
    gemm_kernel<<<4096, 512, 0, stream>>>(Xh, Xl, Ch, Cl, cbq, p16,
                                          max_part, sum_part);
    norm_f16_kernel<<<4096, 256, 0, stream>>>(p16, max_part, sum_part, out);
}